// Round 6
// baseline (4178.626 us; speedup 1.0000x reference)
//
#include <hip/hip_runtime.h>

typedef _Float16 h2_t  __attribute__((ext_vector_type(2)));
typedef _Float16 f16x8 __attribute__((ext_vector_type(8)));
typedef float    f32x4 __attribute__((ext_vector_type(4)));

#define HID  100
#define TENC 4096
#define TDEC 4096
#define NCLS 6
#define NTHR 256   // 4 waves, one per SIMD

__device__ __forceinline__ float sigm(float v)  { return __builtin_amdgcn_rcpf(1.0f + __expf(-v)); }
__device__ __forceinline__ float tanh_(float v) { return 1.0f - 2.0f * __builtin_amdgcn_rcpf(1.0f + __expf(2.0f * v)); }

// lgkm-only barrier: does NOT drain vmcnt, so global stores stay in flight
// across steps (unlike __syncthreads).
#define SYNC_LDS() asm volatile("s_waitcnt lgkmcnt(0)\n\ts_barrier" ::: "memory")

__device__ __forceinline__ float packh2(float a, float b) {
    h2_t p; p[0] = (_Float16)a; p[1] = (_Float16)b;
    return __builtin_bit_cast(float, p);
}

// Persistent single-workgroup LSTM, v10 — matvec moved to the MATRIX pipe.
// R11 analysis: v_dot2_f32_f16 is half-rate on gfx950 -> VALU MAC floor is
// ~416cy/step; chain-splitting (v9) confirmed issue-rate-bound, not latency.
// Design:
//  - weight rows gate-interleaved R = 4*cell + gate -> 400 rows = 25 exact
//    16-row M-tiles. With the VERIFIED C/D layout of mfma_f32_16x16x32
//    (row=(lane>>4)*4+reg, col=lane&15), one lane's 4 C-regs = the 4 gate
//    pre-activations of ONE cell. No cross-lane gate gather.
//  - B operand: h broadcast -> every lane holds h[8*(l>>4)+j]; all 16 D
//    columns identical; col (lane&15) is used as a replica id to spread the
//    wave's 28 cells across lanes (static-index cndmask select tree).
//  - K = 104: h[0..99] + slots {x0,x1,x2,1} with weight cols [Wih | bih+bhh]
//    -> input and bias fused into the same MFMA accumulation.
//  - any k-slot permutation inside the fragment CANCELS (A and B loaded with
//    the same lane->k convention); only A-row=lane&15 is assumed.
//  - waves: w0 tiles 0-6 (28 cells), w1-3 6 tiles (24 cells) = 100 cells.
//  - one lgkm-only barrier per step, h double-buffered by parity as before.
__global__ __launch_bounds__(NTHR, 1)
void lstm_rec(const float* __restrict__ x,      // [TENC*3]
              const int*   __restrict__ y,      // [TDEC]
              const float* __restrict__ eWih,   // [400*3]
              const float* __restrict__ eWhh,   // [400*HID]
              const float* __restrict__ ebih,
              const float* __restrict__ ebhh,
              const float* __restrict__ dWih,   // [400]
              const float* __restrict__ dWhh,
              const float* __restrict__ dbih,
              const float* __restrict__ dbhh,
              float* __restrict__ hsto)         // [(TDEC-1)*HID] decoder h history
{
    __shared__ __align__(16) _Float16 hbuf[2][128];  // [parity][k-slot]: 0-99 h, 100-103 input, 104-127 zero
    __shared__ __align__(8)  uint2    xst[TENC];     // packed f16: {x0,x1},{x2,1}
    __shared__               unsigned yst[TDEC];     // packed f16: {yf,0}

    const int t   = threadIdx.x;
    const int w   = t >> 6;
    const int l   = t & 63;
    const int col = l & 15;     // A-row-in-tile / D-col (replica id)
    const int lg  = l >> 4;     // k-chunk id for A/B; cell-in-tile group for D
    const int nt   = (w == 0) ? 7 : 6;
    const int base = (w == 0) ? 0 : 7 + (w - 1) * 6;
    const int gate = col & 3;   // interleaved row R=16T+col -> gate = R&3

    // ---- stage x (f16 pairs) and y (f16) into LDS; zero h buffers ----
    for (int i = t; i < TENC; i += NTHR) {
        const float a = x[3*i], b = x[3*i+1], cc = x[3*i+2];
        uint2 u;
        u.x = __builtin_bit_cast(unsigned, packh2(a, b));
        u.y = __builtin_bit_cast(unsigned, packh2(cc, 1.0f));
        xst[i] = u;
    }
    for (int i = t; i < TDEC; i += NTHR)
        yst[i] = __builtin_bit_cast(unsigned, packh2((float)y[i], 0.0f));
    if (t < 256) ((_Float16*)hbuf)[t] = (_Float16)0.0f;   // both parities, all 128 slots
    __syncthreads();

    // x_0 into hbuf[0][100..103] (thread 0; published by the SYNC_LDS below)
    if (t == 0) {
        uint2 u;
        u.x = __builtin_bit_cast(unsigned, packh2(x[0], x[1]));
        u.y = __builtin_bit_cast(unsigned, packh2(x[2], 1.0f));
        *(uint2*)&hbuf[0][100] = u;
    }

    // ---- encoder A-fragments: wA[tile][ktile], lane holds W[R=16T+col][k=32kt+8lg+j] ----
    f16x8 wA[7][4];
    #pragma unroll
    for (int tt = 0; tt < 7; ++tt) {
        #pragma unroll
        for (int kt = 0; kt < 4; ++kt) {
            f16x8 a;
            #pragma unroll
            for (int j = 0; j < 8; ++j) {
                float v = 0.0f;
                if (tt < nt) {
                    const int cellA = 4*(base + tt) + (col >> 2);
                    const int wrow  = gate * HID + cellA;
                    const int k     = 32*kt + 8*lg + j;
                    if (k < HID)            v = eWhh[wrow*HID + k];
                    else if (k < HID + 3)   v = eWih[wrow*3 + (k - HID)];
                    else if (k == HID + 3)  v = ebih[wrow] + ebhh[wrow];
                }
                a[j] = (_Float16)v;
            }
            wA[tt][kt] = a;
        }
    }
    SYNC_LDS();

    // this lane's owned cell (replica fan-out): t_sel = col mod nt
    int ts = col;
    if (ts >= nt) ts -= nt;
    if (ts >= nt) ts -= nt;
    const int cell = 4*(base + ts) + lg;

    float c = 0.0f;
    int p = 0;

    // ================ encoder: 4096 steps ================
    for (int s = 0; s < TENC; ++s) {
        const f16x8* hb = (const f16x8*)hbuf[p];
        const f16x8 B0 = hb[ 0 + lg];     // k  0..31 chunk lg
        const f16x8 B1 = hb[ 4 + lg];     // k 32..63
        const f16x8 B2 = hb[ 8 + lg];     // k 64..95
        const f16x8 B3 = hb[12 + lg];     // k 96..127

        // prefetch x_{s+1} into the other parity's input slots
        if (t == 0 && s + 1 < TENC)
            *(uint2*)&hbuf[p ^ 1][100] = xst[s + 1];

        f32x4 acc[7];
        #pragma unroll
        for (int tt = 0; tt < 7; ++tt) {
            if (tt < nt) {
                f32x4 z = {0.0f, 0.0f, 0.0f, 0.0f};
                z = __builtin_amdgcn_mfma_f32_16x16x32_f16(wA[tt][0], B0, z, 0, 0, 0);
                z = __builtin_amdgcn_mfma_f32_16x16x32_f16(wA[tt][1], B1, z, 0, 0, 0);
                z = __builtin_amdgcn_mfma_f32_16x16x32_f16(wA[tt][2], B2, z, 0, 0, 0);
                z = __builtin_amdgcn_mfma_f32_16x16x32_f16(wA[tt][3], B3, z, 0, 0, 0);
                acc[tt] = z;
            }
        }

        // static-index select of this lane's tile quad (rule #20: no runtime idx)
        f32x4 q = acc[0];
        #pragma unroll
        for (int tt = 1; tt < 7; ++tt)
            if (tt < nt && ts == tt) q = acc[tt];

        const float fi = sigm(q[0]), ff = sigm(q[1]), fg = tanh_(q[2]), fo = sigm(q[3]);
        c = ff * c + fi * fg;
        const float hn = fo * tanh_(c);
        if (col < nt)                       // unique writer per cell
            hbuf[p ^ 1][cell] = (_Float16)hn;
        SYNC_LDS();
        p ^= 1;
    }

    // ================ transition: decoder input slot {yf0, 1, 0, 0} ================
    if (t == 0) {
        uint2 v;
        v.x = (yst[0] & 0xFFFFu) | 0x3C000000u;   // {yf0, f16(1.0)}
        v.y = 0u;
        *(uint2*)&hbuf[p][100] = v;
    }

    // ---- decoder A-fragments (reuse wA) ----
    #pragma unroll
    for (int tt = 0; tt < 7; ++tt) {
        #pragma unroll
        for (int kt = 0; kt < 4; ++kt) {
            f16x8 a;
            #pragma unroll
            for (int j = 0; j < 8; ++j) {
                float v = 0.0f;
                if (tt < nt) {
                    const int cellA = 4*(base + tt) + (col >> 2);
                    const int wrow  = gate * HID + cellA;
                    const int k     = 32*kt + 8*lg + j;
                    if (k < HID)            v = dWhh[wrow*HID + k];
                    else if (k == HID)      v = dWih[wrow];
                    else if (k == HID + 1)  v = dbih[wrow] + dbhh[wrow];
                }
                a[j] = (_Float16)v;
            }
            wA[tt][kt] = a;
        }
    }
    SYNC_LDS();

    // ================ decoder: 4095 steps (ratio==1 -> teacher-forced) ================
    for (int s = 0; s < TDEC - 1; ++s) {
        const f16x8* hb = (const f16x8*)hbuf[p];
        const f16x8 B0 = hb[ 0 + lg];
        const f16x8 B1 = hb[ 4 + lg];
        const f16x8 B2 = hb[ 8 + lg];
        const f16x8 B3 = hb[12 + lg];

        if (t == 0 && s + 1 < TDEC - 1) {
            uint2 v;
            v.x = (yst[s + 1] & 0xFFFFu) | 0x3C000000u;
            v.y = 0u;
            *(uint2*)&hbuf[p ^ 1][100] = v;
        }

        f32x4 acc[7];
        #pragma unroll
        for (int tt = 0; tt < 7; ++tt) {
            if (tt < nt) {
                f32x4 z = {0.0f, 0.0f, 0.0f, 0.0f};
                z = __builtin_amdgcn_mfma_f32_16x16x32_f16(wA[tt][0], B0, z, 0, 0, 0);
                z = __builtin_amdgcn_mfma_f32_16x16x32_f16(wA[tt][1], B1, z, 0, 0, 0);
                z = __builtin_amdgcn_mfma_f32_16x16x32_f16(wA[tt][2], B2, z, 0, 0, 0);
                z = __builtin_amdgcn_mfma_f32_16x16x32_f16(wA[tt][3], B3, z, 0, 0, 0);
                acc[tt] = z;
            }
        }

        f32x4 q = acc[0];
        #pragma unroll
        for (int tt = 1; tt < 7; ++tt)
            if (tt < nt && ts == tt) q = acc[tt];

        const float fi = sigm(q[0]), ff = sigm(q[1]), fg = tanh_(q[2]), fo = sigm(q[3]);
        c = ff * c + fi * fg;
        const float hn = fo * tanh_(c);
        if (col < nt) {
            hbuf[p ^ 1][cell] = (_Float16)hn;
            hsto[s * HID + cell] = hn;      // global store, never fenced in-loop
        }
        SYNC_LDS();
        p ^= 1;
    }
    // kernel end-of-dispatch drains the hsto stores before logits_k launches
}

// Parallel logits: out[t][r] = linW[r] . h_t + linb[r], last row zeroed.
__global__ __launch_bounds__(256)
void logits_k(const float* __restrict__ hsto, const float* __restrict__ linW,
              const float* __restrict__ linb, float* __restrict__ out)
{
    const int idx = blockIdx.x * 256 + threadIdx.x;
    if (idx >= TDEC * NCLS) return;
    const int tt = idx / NCLS;
    const int r  = idx % NCLS;
    if (tt >= TDEC - 1) { out[idx] = 0.0f; return; }
    const float* h  = hsto + tt * HID;
    const float* wr = linW + r * HID;
    float a = linb[r];
    #pragma unroll 4
    for (int k = 0; k < HID; ++k) a += wr[k] * h[k];
    out[idx] = a;
}

extern "C" void kernel_launch(void* const* d_in, const int* in_sizes, int n_in,
                              void* d_out, int out_size, void* d_ws, size_t ws_size,
                              hipStream_t stream)
{
    const float* x    = (const float*)d_in[0];
    const int*   y    = (const int*)  d_in[1];
    const float* eWih = (const float*)d_in[2];
    const float* eWhh = (const float*)d_in[3];
    const float* ebih = (const float*)d_in[4];
    const float* ebhh = (const float*)d_in[5];
    const float* dWih = (const float*)d_in[6];
    const float* dWhh = (const float*)d_in[7];
    const float* dbih = (const float*)d_in[8];
    const float* dbhh = (const float*)d_in[9];
    const float* linW = (const float*)d_in[10];
    const float* linb = (const float*)d_in[11];
    float* out  = (float*)d_out;
    float* hsto = (float*)d_ws;   // (TDEC-1)*HID*4 = 1.64 MB scratch

    lstm_rec<<<dim3(1), dim3(NTHR), 0, stream>>>(
        x, y, eWih, eWhh, ebih, ebhh, dWih, dWhh, dbih, dbhh, hsto);

    const int nout = TDEC * NCLS;
    logits_k<<<dim3((nout + 255) / 256), dim3(256), 0, stream>>>(hsto, linW, linb, out);
}